// Round 4
// baseline (203.319 us; speedup 1.0000x reference)
//
#include <hip/hip_runtime.h>
#include <hip/hip_bf16.h>
#include <stdint.h>

typedef __attribute__((ext_vector_type(8))) short bf16x8;
typedef __attribute__((ext_vector_type(8))) _Float16 f16x8;
typedef __attribute__((ext_vector_type(4))) _Float16 f16x4;
typedef __attribute__((ext_vector_type(4))) float f32x4;

static constexpr int BATCH = 2;
static constexpr int SEQ = 2048;
static constexpr int EMB = 1024;
static constexpr int NH = 16;
static constexpr int HD_ = 64;

#define AS1 __attribute__((address_space(1)))
#define AS3 __attribute__((address_space(3)))

__device__ __forceinline__ void gload_lds16(const void* g, void* l) {
  __builtin_amdgcn_global_load_lds((const AS1 uint32_t*)g, (AS3 uint32_t*)l, 16, 0, 0);
}

__device__ __forceinline__ f32x4 mfma16(bf16x8 a, bf16x8 b, f32x4 c) {
  return __builtin_amdgcn_mfma_f32_16x16x32_bf16(a, b, c, 0, 0, 0);
}
__device__ __forceinline__ f32x4 mfma16(f16x8 a, f16x8 b, f32x4 c) {
  return __builtin_amdgcn_mfma_f32_16x16x32_f16(a, b, c, 0, 0, 0);
}

template <int MODE> struct elem_of { using t = __hip_bfloat16; };
template <> struct elem_of<1> { using t = _Float16; };
template <typename E> struct v8t;
template <> struct v8t<__hip_bfloat16> { using t = bf16x8; };
template <> struct v8t<_Float16> { using t = f16x8; };

// ---------------- convert f32 -> bf16 hi/lo split ----------------
__global__ __launch_bounds__(256) void k_convert_split(const float* __restrict__ in,
                                                       __hip_bfloat16* __restrict__ oh,
                                                       __hip_bfloat16* __restrict__ ol,
                                                       int n4) {
  int idx = blockIdx.x * 256 + threadIdx.x;
  if (idx >= n4) return;
  float4 v = reinterpret_cast<const float4*>(in)[idx];
  const float* f = reinterpret_cast<const float*>(&v);
  __hip_bfloat16 h[4], l[4];
#pragma unroll
  for (int i = 0; i < 4; ++i) {
    h[i] = __float2bfloat16(f[i]);
    l[i] = __float2bfloat16(f[i] - __bfloat162float(h[i]));
  }
  reinterpret_cast<uint2*>(oh)[idx] = *reinterpret_cast<uint2*>(h);
  reinterpret_cast<uint2*>(ol)[idx] = *reinterpret_cast<uint2*>(l);
}

// ---------------- transpose+convert ----------------
// TM 0: Wqkv -> bf16 hi/lo, rows permuted to [q(1024) | k(1024) | v(1024)]
// TM 1: Wproj -> f16 single, no perm
template <int TM>
__global__ __launch_bounds__(256) void k_transpose(const float* __restrict__ in,
                                                   void* __restrict__ oh_,
                                                   void* __restrict__ ol_, int R, int C) {
  __shared__ float tile[32][33];
  const int t = threadIdx.x;
  const int tr = t >> 5, tc = t & 31;
  const int r0 = blockIdx.y * 32, c0 = blockIdx.x * 32;
#pragma unroll
  for (int rr = 0; rr < 32; rr += 8)
    tile[tr + rr][tc] = in[(size_t)(r0 + tr + rr) * C + c0 + tc];
  __syncthreads();
#pragma unroll
  for (int rr = 0; rr < 32; rr += 8) {
    const int c = c0 + tr + rr;
    const float v = tile[tc][tr + rr];
    if constexpr (TM == 0) {
      const int h = c / 192, r = c - h * 192;
      const int d = (r < 64) ? h * 64 + r
                             : (r < 128 ? 1024 + h * 64 + (r - 64)
                                        : 2048 + h * 64 + (r - 128));
      const __hip_bfloat16 hi = __float2bfloat16(v);
      ((__hip_bfloat16*)oh_)[(size_t)d * R + r0 + tc] = hi;
      ((__hip_bfloat16*)ol_)[(size_t)d * R + r0 + tc] =
          __float2bfloat16(v - __bfloat162float(hi));
    } else {
      ((_Float16*)oh_)[(size_t)c * R + r0 + tc] = (_Float16)v;
    }
  }
}

// ---------------- 128x128 GEMM (A[M][K] * Bt[N][K]^T) ----------------
// MODE 0 (bf16, SPLIT=1): QK epilogue -> q_s f16 (x8*log2e), k_s f16
// MODE 2 (bf16, SPLIT=0): V epilogue -> v_t f16 transposed
// MODE 1 (f16,  SPLIT=0): proj epilogue -> f32 + bias
template <int MODE, int SPLIT>
__global__ __launch_bounds__(256) void k_gemm(
    const void* __restrict__ Ah_, const void* __restrict__ Al_,
    const void* __restrict__ Bh_, const void* __restrict__ Bl_,
    const float* __restrict__ bias, int M, int N, int K, void* __restrict__ o1_,
    void* __restrict__ o2_, float* __restrict__ of) {
  using E = typename elem_of<MODE>::t;
  using V8 = typename v8t<E>::t;
  const E* Ah = (const E*)Ah_;
  const E* Al = (const E*)Al_;
  const E* Bh = (const E*)Bh_;
  const E* Bl = (const E*)Bl_;
  __shared__ E AsH[2][128 * 32];
  __shared__ E BsH[2][128 * 32];
  __shared__ E AsL[SPLIT ? 2 : 1][128 * 32];
  __shared__ E BsL[SPLIT ? 2 : 1][128 * 32];
  const int t = threadIdx.x;
  const int l = t & 63, w = t >> 6;
  const int lr = l & 15, lg = l >> 4;
  const int wr = w >> 1, wc = w & 1;
  const int m0 = blockIdx.y * 128, n0 = blockIdx.x * 128;

  auto stage = [&](int buf, int k0) {
#pragma unroll
    for (int j = 0; j < 2; ++j) {
      const int c = t + 256 * j;
      const int row = c >> 2, cb = c & 3;
      const size_t ga = (size_t)(m0 + row) * K + k0 + cb * 8;
      const size_t gb = (size_t)(n0 + row) * K + k0 + cb * 8;
      gload_lds16(Ah + ga, &AsH[buf][c * 8]);
      gload_lds16(Bh + gb, &BsH[buf][c * 8]);
      if constexpr (SPLIT) {
        gload_lds16(Al + ga, &AsL[buf][c * 8]);
        gload_lds16(Bl + gb, &BsL[buf][c * 8]);
      }
    }
  };

  f32x4 acc[4][4];
#pragma unroll
  for (int m = 0; m < 4; ++m)
#pragma unroll
    for (int n = 0; n < 4; ++n) acc[m][n] = f32x4{0.f, 0.f, 0.f, 0.f};

  stage(0, 0);
  const int NT = K / 32;
  int cur = 0;
  for (int kt = 0; kt < NT; ++kt) {
    __syncthreads();
    if (kt + 1 < NT) stage(cur ^ 1, (kt + 1) * 32);
    V8 afh[4], bfh[4], afl[4], bfl[4];
#pragma unroll
    for (int m = 0; m < 4; ++m) {
      const int off = (wr * 64 + m * 16 + lr) * 32 + lg * 8;
      afh[m] = *(const V8*)&AsH[cur][off];
      if constexpr (SPLIT) afl[m] = *(const V8*)&AsL[cur][off];
    }
#pragma unroll
    for (int n = 0; n < 4; ++n) {
      const int off = (wc * 64 + n * 16 + lr) * 32 + lg * 8;
      bfh[n] = *(const V8*)&BsH[cur][off];
      if constexpr (SPLIT) bfl[n] = *(const V8*)&BsL[cur][off];
    }
#pragma unroll
    for (int m = 0; m < 4; ++m)
#pragma unroll
      for (int n = 0; n < 4; ++n) {
        acc[m][n] = mfma16(afh[m], bfh[n], acc[m][n]);
        if constexpr (SPLIT) {
          acc[m][n] = mfma16(afh[m], bfl[n], acc[m][n]);
          acc[m][n] = mfma16(afl[m], bfh[n], acc[m][n]);
        }
      }
    cur ^= 1;
  }

#pragma unroll
  for (int m = 0; m < 4; ++m) {
#pragma unroll
    for (int n = 0; n < 4; ++n) {
#pragma unroll
      for (int i = 0; i < 4; ++i) {
        const int row = m0 + wr * 64 + m * 16 + lg * 4 + i;
        const int col = n0 + wc * 64 + n * 16 + lr;
        if constexpr (MODE == 0) {
          // cols [0,1024)=q, [1024,2048)=k (permuted W); bias remap to original
          const int cc = col & 1023;
          const int h = cc >> 6, r = cc & 63;
          const float bv = bias[h * 192 + (col < 1024 ? 0 : 64) + r];
          const float v = acc[m][n][i] + bv;
          const int b = row >> 11, s = row & (SEQ - 1);
          const size_t dst = (((size_t)b * NH + h) * SEQ + s) * HD_ + r;
          if (col < 1024)
            ((_Float16*)o1_)[dst] = (_Float16)(v * 11.5415603f);  // q: 8*log2(e) folded
          else
            ((_Float16*)o2_)[dst] = (_Float16)v;  // k
        } else if constexpr (MODE == 2) {
          const int h = col >> 6, r = col & 63;
          const float v = acc[m][n][i] + bias[h * 192 + 128 + r];
          const int b = row >> 11, s = row & (SEQ - 1);
          ((_Float16*)o1_)[(((size_t)b * NH + h) * HD_ + r) * SEQ + s] = (_Float16)v;
        } else {
          of[(size_t)row * N + col] = acc[m][n][i] + bias[col];
        }
      }
    }
  }
}

// ---------------- flash attention, f16, swapped QK^T, dbuf + async stage ----------------
// qs: [BH][S][64] f16 (x 8*log2e folded); ks: [BH][S][64]; vt: [BH][64][S]
// ao: [B][S][E] f16. Logits/softmax in base-2 (exp2).
__global__ __launch_bounds__(256) void k_attn(const _Float16* __restrict__ qs,
                                              const _Float16* __restrict__ ks,
                                              const _Float16* __restrict__ vt,
                                              _Float16* __restrict__ ao) {
  __shared__ _Float16 Kt[2][64][72];   // [buf][kv][d], +8 pad
  __shared__ _Float16 Vt[2][64][72];   // [buf][d][kv]
  __shared__ _Float16 Pl[4][16][72];   // per-wave P: [q][kv]
  const int t = threadIdx.x;
  const int l = t & 63, w = t >> 6;
  const int lr = l & 15, lg = l >> 4;
  // XCD-grouping swizzle: all 32 q-blocks of a head land on one XCD (8 XCDs,
  // 1024 blocks round-robin): id%8 picks XCD; give each XCD 4 whole heads.
  const int id = blockIdx.x;
  const int xc = id & 7, m_ = id >> 3;
  const int bh = xc + 8 * (m_ >> 5);
  const int qb = (m_ & 31) * 64 + w * 16;

  // Q fragments (B-operand: n=q=lr, k=d)
  const size_t qoff = ((size_t)bh * SEQ + qb + lr) * HD_;
  const f16x8 qf0 = *(const f16x8*)(qs + qoff + lg * 8);
  const f16x8 qf1 = *(const f16x8*)(qs + qoff + 32 + lg * 8);

  // staging geometry: thread t covers rows {t>>3, (t>>3)+32}, col-block t&7
  const int srow = t >> 3, scb = t & 7;
  const _Float16* kbase = ks + (size_t)bh * SEQ * HD_;
  const _Float16* vbase = vt + (size_t)bh * HD_ * SEQ;

  f16x8 gk0, gk1, gv0, gv1;
  auto gload = [&](int kv0) {
    gk0 = *(const f16x8*)(kbase + (size_t)(kv0 + srow) * HD_ + scb * 8);
    gk1 = *(const f16x8*)(kbase + (size_t)(kv0 + srow + 32) * HD_ + scb * 8);
    gv0 = *(const f16x8*)(vbase + (size_t)srow * SEQ + kv0 + scb * 8);
    gv1 = *(const f16x8*)(vbase + (size_t)(srow + 32) * SEQ + kv0 + scb * 8);
  };
  auto swrite = [&](int buf) {
    *(f16x8*)&Kt[buf][srow][scb * 8] = gk0;
    *(f16x8*)&Kt[buf][srow + 32][scb * 8] = gk1;
    *(f16x8*)&Vt[buf][srow][scb * 8] = gv0;
    *(f16x8*)&Vt[buf][srow + 32][scb * 8] = gv1;
  };

  gload(0);
  swrite(0);

  float mr = -1e30f, lsum = 0.f;
  f32x4 oacc[4];
#pragma unroll
  for (int n = 0; n < 4; ++n) oacc[n] = f32x4{0.f, 0.f, 0.f, 0.f};

  const int NT = SEQ / 64;
  for (int it = 0; it < NT; ++it) {
    const int cur = it & 1;
    __syncthreads();  // buf[cur] staged (prev iter / prologue) now visible
    if (it + 1 < NT) gload((it + 1) * 64);  // issue early; consumed at iter end

    // S^T = K Q^T : lane holds S[kv=16*t4+4*lg+i][q=lr]   (base-2 logits)
    f32x4 sa[4];
    __builtin_amdgcn_s_setprio(1);
#pragma unroll
    for (int t4 = 0; t4 < 4; ++t4) {
      const f16x8 kf0 = *(const f16x8*)&Kt[cur][t4 * 16 + lr][lg * 8];
      const f16x8 kf1 = *(const f16x8*)&Kt[cur][t4 * 16 + lr][32 + lg * 8];
      f32x4 s = mfma16(kf0, qf0, f32x4{0.f, 0.f, 0.f, 0.f});
      sa[t4] = mfma16(kf1, qf1, s);
    }
    __builtin_amdgcn_s_setprio(0);

    // online softmax (per-lane q-row), defer-max with THR=8 (base-2)
    float t01 = fmaxf(fmaxf(sa[0][0], sa[0][1]), fmaxf(sa[0][2], sa[0][3]));
    float t23 = fmaxf(fmaxf(sa[1][0], sa[1][1]), fmaxf(sa[1][2], sa[1][3]));
    float t45 = fmaxf(fmaxf(sa[2][0], sa[2][1]), fmaxf(sa[2][2], sa[2][3]));
    float t67 = fmaxf(fmaxf(sa[3][0], sa[3][1]), fmaxf(sa[3][2], sa[3][3]));
    float tm = fmaxf(fmaxf(t01, t23), fmaxf(t45, t67));
    tm = fmaxf(tm, __shfl_xor(tm, 16));
    tm = fmaxf(tm, __shfl_xor(tm, 32));

    if (__any(tm > mr + 8.0f)) {  // wave-uniform rescale
      const float nm = fmaxf(mr, tm);
      const float corr = exp2f(mr - nm);
      mr = nm;
      lsum *= corr;
      float cb4[4];
#pragma unroll
      for (int i = 0; i < 4; ++i)
        cb4[i] = __shfl(corr, (l & 48) + ((l >> 4) << 2) + i);
#pragma unroll
      for (int n = 0; n < 4; ++n)
#pragma unroll
        for (int i = 0; i < 4; ++i) oacc[n][i] *= cb4[i];
    }

    float ts = 0.f;
#pragma unroll
    for (int t4 = 0; t4 < 4; ++t4) {
      f16x4 pp;
#pragma unroll
      for (int i = 0; i < 4; ++i) {
        const float p = exp2f(sa[t4][i] - mr);
        ts += p;
        pp[i] = (_Float16)p;
      }
      *(f16x4*)&Pl[w][lr][t4 * 16 + lg * 4] = pp;
    }
    ts += __shfl_xor(ts, 16);
    ts += __shfl_xor(ts, 32);
    lsum += ts;

    // O += P V (A=P[q][kv], B=V^T[d][kv])
    const f16x8 aP0 = *(const f16x8*)&Pl[w][lr][lg * 8];
    const f16x8 aP1 = *(const f16x8*)&Pl[w][lr][32 + lg * 8];
    __builtin_amdgcn_s_setprio(1);
#pragma unroll
    for (int n = 0; n < 4; ++n) {
      const f16x8 bv0 = *(const f16x8*)&Vt[cur][n * 16 + lr][lg * 8];
      const f16x8 bv1 = *(const f16x8*)&Vt[cur][n * 16 + lr][32 + lg * 8];
      oacc[n] = mfma16(aP0, bv0, oacc[n]);
      oacc[n] = mfma16(aP1, bv1, oacc[n]);
    }
    __builtin_amdgcn_s_setprio(0);

    if (it + 1 < NT) swrite(cur ^ 1);  // vmcnt waits land here, hidden by compute
  }

  // epilogue: fetch lsum for q=4*lg+i, normalize, store f16
  float ls4[4];
#pragma unroll
  for (int i = 0; i < 4; ++i)
    ls4[i] = __shfl(lsum, (l & 48) + ((l >> 4) << 2) + i);
  const int b = bh >> 4, h = bh & 15;
#pragma unroll
  for (int n = 0; n < 4; ++n)
#pragma unroll
    for (int i = 0; i < 4; ++i) {
      const int row = qb + ((l >> 4) << 2) + i;
      ao[((size_t)b * SEQ + row) * EMB + h * HD_ + n * 16 + lr] =
          (_Float16)(oacc[n][i] / ls4[i]);
    }
}

extern "C" void kernel_launch(void* const* d_in, const int* in_sizes, int n_in,
                              void* d_out, int out_size, void* d_ws, size_t ws_size,
                              hipStream_t stream) {
  const float* query = (const float*)d_in[0];
  const float* Wqkv = (const float*)d_in[3];
  const float* bqkv = (const float*)d_in[4];
  const float* Wproj = (const float*)d_in[5];
  const float* bproj = (const float*)d_in[6];
  float* out = (float*)d_out;

  char* ws = (char*)d_ws;
  const size_t MB = 1024 * 1024;
  __hip_bfloat16* q_hi    = (__hip_bfloat16*)(ws + 0);        // 8MB; dead after QKV GEMMs
  __hip_bfloat16* q_lo    = (__hip_bfloat16*)(ws + 8 * MB);   // 8MB; dead after QK GEMM
  __hip_bfloat16* Wqkv_th = (__hip_bfloat16*)(ws + 16 * MB);  // 6MB (rows: q|k|v)
  __hip_bfloat16* Wqkv_tl = (__hip_bfloat16*)(ws + 22 * MB);  // 6MB
  _Float16* q_s           = (_Float16*)(ws + 28 * MB);        // 8MB [32][2048][64]
  _Float16* k_s           = (_Float16*)(ws + 36 * MB);        // 8MB
  _Float16* v_t           = (_Float16*)(ws + 44 * MB);        // 8MB [32][64][2048]
  _Float16* a_o           = (_Float16*)(ws + 0);              // aliases q_hi
  _Float16* Wproj_t       = (_Float16*)(ws + 8 * MB);         // aliases q_lo

  const int M = BATCH * SEQ;  // 4096
  k_convert_split<<<(M * EMB / 4 + 255) / 256, 256, 0, stream>>>(query, q_hi, q_lo,
                                                                 M * EMB / 4);
  k_transpose<0><<<dim3(3 * EMB / 32, EMB / 32), 256, 0, stream>>>(Wqkv, Wqkv_th,
                                                                   Wqkv_tl, EMB, 3 * EMB);
  // q,k columns: split-bf16 precision (3 MFMA)
  k_gemm<0, 1><<<dim3(16, M / 128), 256, 0, stream>>>(
      q_hi, q_lo, Wqkv_th, Wqkv_tl, bqkv, M, 2048, EMB, q_s, k_s, nullptr);
  // v columns: single bf16 (1 MFMA)
  k_gemm<2, 0><<<dim3(8, M / 128), 256, 0, stream>>>(
      q_hi, nullptr, Wqkv_th + (size_t)2048 * EMB, nullptr, bqkv, M, 1024, EMB, v_t,
      nullptr, nullptr);
  k_transpose<1><<<dim3(EMB / 32, EMB / 32), 256, 0, stream>>>(Wproj, Wproj_t, nullptr,
                                                               EMB, EMB);
  k_attn<<<dim3(1024), 256, 0, stream>>>(q_s, k_s, v_t, a_o);
  k_gemm<1, 0><<<dim3(EMB / 128, M / 128), 256, 0, stream>>>(
      a_o, nullptr, Wproj_t, nullptr, bproj, M, EMB, EMB, nullptr, nullptr, out);
}

// Round 5
// 196.494 us; speedup vs baseline: 1.0347x; 1.0347x over previous
//
#include <hip/hip_runtime.h>
#include <hip/hip_bf16.h>
#include <stdint.h>

typedef __attribute__((ext_vector_type(8))) short bf16x8;
typedef __attribute__((ext_vector_type(8))) _Float16 f16x8;
typedef __attribute__((ext_vector_type(4))) _Float16 f16x4;
typedef __attribute__((ext_vector_type(4))) float f32x4;

static constexpr int BATCH = 2;
static constexpr int SEQ = 2048;
static constexpr int EMB = 1024;
static constexpr int NH = 16;
static constexpr int HD_ = 64;

#define AS1 __attribute__((address_space(1)))
#define AS3 __attribute__((address_space(3)))

__device__ __forceinline__ void gload_lds16(const void* g, void* l) {
  __builtin_amdgcn_global_load_lds((const AS1 uint32_t*)g, (AS3 uint32_t*)l, 16, 0, 0);
}

__device__ __forceinline__ f32x4 mfma16(bf16x8 a, bf16x8 b, f32x4 c) {
  return __builtin_amdgcn_mfma_f32_16x16x32_bf16(a, b, c, 0, 0, 0);
}
__device__ __forceinline__ f32x4 mfma16(f16x8 a, f16x8 b, f32x4 c) {
  return __builtin_amdgcn_mfma_f32_16x16x32_f16(a, b, c, 0, 0, 0);
}

// swizzled 16B-block read from a 128B-row LDS tile: byte ^= (row&7)<<4
__device__ __forceinline__ f16x8 swzread(const _Float16* base, int row, int blk) {
  return *(const f16x8*)((const char*)base + row * 128 +
                         ((blk * 16) ^ ((row & 7) << 4)));
}

template <int MODE> struct elem_of { using t = __hip_bfloat16; };
template <> struct elem_of<1> { using t = _Float16; };
template <typename E> struct v8t;
template <> struct v8t<__hip_bfloat16> { using t = bf16x8; };
template <> struct v8t<_Float16> { using t = f16x8; };

// ---------------- convert f32 -> bf16 hi/lo split ----------------
__global__ __launch_bounds__(256) void k_convert_split(const float* __restrict__ in,
                                                       __hip_bfloat16* __restrict__ oh,
                                                       __hip_bfloat16* __restrict__ ol,
                                                       int n4) {
  int idx = blockIdx.x * 256 + threadIdx.x;
  if (idx >= n4) return;
  float4 v = reinterpret_cast<const float4*>(in)[idx];
  const float* f = reinterpret_cast<const float*>(&v);
  __hip_bfloat16 h[4], l[4];
#pragma unroll
  for (int i = 0; i < 4; ++i) {
    h[i] = __float2bfloat16(f[i]);
    l[i] = __float2bfloat16(f[i] - __bfloat162float(h[i]));
  }
  reinterpret_cast<uint2*>(oh)[idx] = *reinterpret_cast<uint2*>(h);
  reinterpret_cast<uint2*>(ol)[idx] = *reinterpret_cast<uint2*>(l);
}

// ---------------- transpose+convert ----------------
// TM 0: Wqkv -> bf16 hi/lo, rows permuted to [q(1024) | k(1024) | v(1024)]
// TM 1: Wproj -> f16 single, no perm
template <int TM>
__global__ __launch_bounds__(256) void k_transpose(const float* __restrict__ in,
                                                   void* __restrict__ oh_,
                                                   void* __restrict__ ol_, int R, int C) {
  __shared__ float tile[32][33];
  const int t = threadIdx.x;
  const int tr = t >> 5, tc = t & 31;
  const int r0 = blockIdx.y * 32, c0 = blockIdx.x * 32;
#pragma unroll
  for (int rr = 0; rr < 32; rr += 8)
    tile[tr + rr][tc] = in[(size_t)(r0 + tr + rr) * C + c0 + tc];
  __syncthreads();
#pragma unroll
  for (int rr = 0; rr < 32; rr += 8) {
    const int c = c0 + tr + rr;
    const float v = tile[tc][tr + rr];
    if constexpr (TM == 0) {
      const int h = c / 192, r = c - h * 192;
      const int d = (r < 64) ? h * 64 + r
                             : (r < 128 ? 1024 + h * 64 + (r - 64)
                                        : 2048 + h * 64 + (r - 128));
      const __hip_bfloat16 hi = __float2bfloat16(v);
      ((__hip_bfloat16*)oh_)[(size_t)d * R + r0 + tc] = hi;
      ((__hip_bfloat16*)ol_)[(size_t)d * R + r0 + tc] =
          __float2bfloat16(v - __bfloat162float(hi));
    } else {
      ((_Float16*)oh_)[(size_t)c * R + r0 + tc] = (_Float16)v;
    }
  }
}

// ---------------- 128x128 GEMM (A[M][K] * Bt[N][K]^T) ----------------
// MODE 0 (bf16, SPLIT=1): QK epilogue -> q_s f16 (x8*log2e), k_s f16
// MODE 2 (bf16, SPLIT=0): V epilogue -> v_t f16 transposed
// MODE 1 (f16,  SPLIT=0): proj epilogue -> f32 + bias
template <int MODE, int SPLIT>
__global__ __launch_bounds__(256) void k_gemm(
    const void* __restrict__ Ah_, const void* __restrict__ Al_,
    const void* __restrict__ Bh_, const void* __restrict__ Bl_,
    const float* __restrict__ bias, int M, int N, int K, void* __restrict__ o1_,
    void* __restrict__ o2_, float* __restrict__ of) {
  using E = typename elem_of<MODE>::t;
  using V8 = typename v8t<E>::t;
  const E* Ah = (const E*)Ah_;
  const E* Al = (const E*)Al_;
  const E* Bh = (const E*)Bh_;
  const E* Bl = (const E*)Bl_;
  __shared__ E AsH[2][128 * 32];
  __shared__ E BsH[2][128 * 32];
  __shared__ E AsL[SPLIT ? 2 : 1][128 * 32];
  __shared__ E BsL[SPLIT ? 2 : 1][128 * 32];
  const int t = threadIdx.x;
  const int l = t & 63, w = t >> 6;
  const int lr = l & 15, lg = l >> 4;
  const int wr = w >> 1, wc = w & 1;
  const int m0 = blockIdx.y * 128, n0 = blockIdx.x * 128;

  auto stage = [&](int buf, int k0) {
#pragma unroll
    for (int j = 0; j < 2; ++j) {
      const int c = t + 256 * j;
      const int row = c >> 2, cb = c & 3;
      const size_t ga = (size_t)(m0 + row) * K + k0 + cb * 8;
      const size_t gb = (size_t)(n0 + row) * K + k0 + cb * 8;
      gload_lds16(Ah + ga, &AsH[buf][c * 8]);
      gload_lds16(Bh + gb, &BsH[buf][c * 8]);
      if constexpr (SPLIT) {
        gload_lds16(Al + ga, &AsL[buf][c * 8]);
        gload_lds16(Bl + gb, &BsL[buf][c * 8]);
      }
    }
  };

  f32x4 acc[4][4];
#pragma unroll
  for (int m = 0; m < 4; ++m)
#pragma unroll
    for (int n = 0; n < 4; ++n) acc[m][n] = f32x4{0.f, 0.f, 0.f, 0.f};

  stage(0, 0);
  const int NT = K / 32;
  int cur = 0;
  for (int kt = 0; kt < NT; ++kt) {
    __syncthreads();
    if (kt + 1 < NT) stage(cur ^ 1, (kt + 1) * 32);
    V8 afh[4], bfh[4], afl[4], bfl[4];
#pragma unroll
    for (int m = 0; m < 4; ++m) {
      const int off = (wr * 64 + m * 16 + lr) * 32 + lg * 8;
      afh[m] = *(const V8*)&AsH[cur][off];
      if constexpr (SPLIT) afl[m] = *(const V8*)&AsL[cur][off];
    }
#pragma unroll
    for (int n = 0; n < 4; ++n) {
      const int off = (wc * 64 + n * 16 + lr) * 32 + lg * 8;
      bfh[n] = *(const V8*)&BsH[cur][off];
      if constexpr (SPLIT) bfl[n] = *(const V8*)&BsL[cur][off];
    }
#pragma unroll
    for (int m = 0; m < 4; ++m)
#pragma unroll
      for (int n = 0; n < 4; ++n) {
        acc[m][n] = mfma16(afh[m], bfh[n], acc[m][n]);
        if constexpr (SPLIT) {
          acc[m][n] = mfma16(afh[m], bfl[n], acc[m][n]);
          acc[m][n] = mfma16(afl[m], bfh[n], acc[m][n]);
        }
      }
    cur ^= 1;
  }

#pragma unroll
  for (int m = 0; m < 4; ++m) {
#pragma unroll
    for (int n = 0; n < 4; ++n) {
#pragma unroll
      for (int i = 0; i < 4; ++i) {
        const int row = m0 + wr * 64 + m * 16 + lg * 4 + i;
        const int col = n0 + wc * 64 + n * 16 + lr;
        if constexpr (MODE == 0) {
          // cols [0,1024)=q, [1024,2048)=k (permuted W); bias remap to original
          const int cc = col & 1023;
          const int h = cc >> 6, r = cc & 63;
          const float bv = bias[h * 192 + (col < 1024 ? 0 : 64) + r];
          const float v = acc[m][n][i] + bv;
          const int b = row >> 11, s = row & (SEQ - 1);
          const size_t dst = (((size_t)b * NH + h) * SEQ + s) * HD_ + r;
          if (col < 1024)
            ((_Float16*)o1_)[dst] = (_Float16)(v * 11.5415603f);  // q: 8*log2(e) folded
          else
            ((_Float16*)o2_)[dst] = (_Float16)v;  // k
        } else if constexpr (MODE == 2) {
          const int h = col >> 6, r = col & 63;
          const float v = acc[m][n][i] + bias[h * 192 + 128 + r];
          const int b = row >> 11, s = row & (SEQ - 1);
          ((_Float16*)o1_)[(((size_t)b * NH + h) * HD_ + r) * SEQ + s] = (_Float16)v;
        } else {
          of[(size_t)row * N + col] = acc[m][n][i] + bias[col];
        }
      }
    }
  }
}

// ---------------- flash attention, f16, swapped QK^T ----------------
// async-DMA dbuf staging (global_load_lds) + T21 XOR-swizzled LDS (no pads,
// 40KB -> 4 blocks/CU), 1 barrier/iter, base-2 softmax with defer-max.
// qs: [BH][S][64] f16 (x 8*log2e folded); ks: [BH][S][64]; vt: [BH][64][S]
__global__ __launch_bounds__(256) void k_attn(const _Float16* __restrict__ qs,
                                              const _Float16* __restrict__ ks,
                                              const _Float16* __restrict__ vt,
                                              _Float16* __restrict__ ao) {
  __shared__ _Float16 Kt[2][64][64];   // [buf][kv][d]   swizzled rows (128B)
  __shared__ _Float16 Vt[2][64][64];   // [buf][d][kv]   swizzled rows
  __shared__ _Float16 Pl[4][16][64];   // per-wave P [q][kv], swizzled rows
  const int t = threadIdx.x;
  const int l = t & 63, w = t >> 6;
  const int lr = l & 15, lg = l >> 4;
  // XCD-grouping swizzle: 4 whole heads per XCD -> K/V L2-resident
  const int id = blockIdx.x;
  const int xc = id & 7, m_ = id >> 3;
  const int bh = xc + 8 * (m_ >> 5);
  const int qb = (m_ & 31) * 64 + w * 16;

  // Q fragments (B-operand: n=q=lr, k=d)
  const size_t qoff = ((size_t)bh * SEQ + qb + lr) * HD_;
  const f16x8 qf0 = *(const f16x8*)(qs + qoff + lg * 8);
  const f16x8 qf1 = *(const f16x8*)(qs + qoff + 32 + lg * 8);

  const _Float16* kbase = ks + (size_t)bh * SEQ * HD_;
  const _Float16* vbase = vt + (size_t)bh * HD_ * SEQ;

  // async staging: thread t -> rows {t>>3, t>>3+32}, 16B-block cb = t&7.
  // LDS dest linear; SOURCE block pre-swizzled (cb ^ (row&7)) so that the
  // swizzled read (blk ^ (row&7)) returns the original data (T21 involution).
  const int srow = t >> 3, scb = t & 7;
  auto stage = [&](int buf, int kv0) {
    const int r0 = srow, r1 = srow + 32;
    gload_lds16(kbase + (size_t)(kv0 + r0) * HD_ + (scb ^ (r0 & 7)) * 8,
                &Kt[buf][r0][scb * 8]);
    gload_lds16(kbase + (size_t)(kv0 + r1) * HD_ + (scb ^ (r1 & 7)) * 8,
                &Kt[buf][r1][scb * 8]);
    gload_lds16(vbase + (size_t)r0 * SEQ + kv0 + (scb ^ (r0 & 7)) * 8,
                &Vt[buf][r0][scb * 8]);
    gload_lds16(vbase + (size_t)r1 * SEQ + kv0 + (scb ^ (r1 & 7)) * 8,
                &Vt[buf][r1][scb * 8]);
  };

  stage(0, 0);

  float mr = -1e30f, lsum = 0.f;
  f32x4 oacc[4];
#pragma unroll
  for (int n = 0; n < 4; ++n) oacc[n] = f32x4{0.f, 0.f, 0.f, 0.f};

  const int NT = SEQ / 64;
  for (int it = 0; it < NT; ++it) {
    const int cur = it & 1;
    __syncthreads();  // drains vmcnt: buf[cur] DMA complete; prev reads done
    if (it + 1 < NT) stage(cur ^ 1, (it + 1) * 64);  // async, lands by next barrier

    // S^T = K Q^T : lane holds S[kv=16*t4+4*lg+i][q=lr]   (base-2 logits)
    f32x4 sa[4];
    __builtin_amdgcn_s_setprio(1);
#pragma unroll
    for (int t4 = 0; t4 < 4; ++t4) {
      const int r = t4 * 16 + lr;
      const f16x8 kf0 = swzread(&Kt[cur][0][0], r, lg);
      const f16x8 kf1 = swzread(&Kt[cur][0][0], r, lg + 4);
      f32x4 s = mfma16(kf0, qf0, f32x4{0.f, 0.f, 0.f, 0.f});
      sa[t4] = mfma16(kf1, qf1, s);
    }
    __builtin_amdgcn_s_setprio(0);

    // online softmax (per-lane q-row), defer-max with THR=8 (base-2)
    float t01 = fmaxf(fmaxf(sa[0][0], sa[0][1]), fmaxf(sa[0][2], sa[0][3]));
    float t23 = fmaxf(fmaxf(sa[1][0], sa[1][1]), fmaxf(sa[1][2], sa[1][3]));
    float t45 = fmaxf(fmaxf(sa[2][0], sa[2][1]), fmaxf(sa[2][2], sa[2][3]));
    float t67 = fmaxf(fmaxf(sa[3][0], sa[3][1]), fmaxf(sa[3][2], sa[3][3]));
    float tm = fmaxf(fmaxf(t01, t23), fmaxf(t45, t67));
    tm = fmaxf(tm, __shfl_xor(tm, 16));
    tm = fmaxf(tm, __shfl_xor(tm, 32));

    if (__any(tm > mr + 8.0f)) {  // wave-uniform rescale
      const float nm = fmaxf(mr, tm);
      const float corr = exp2f(mr - nm);
      mr = nm;
      lsum *= corr;
      float cb4[4];
#pragma unroll
      for (int i = 0; i < 4; ++i)
        cb4[i] = __shfl(corr, (l & 48) + ((l >> 4) << 2) + i);
#pragma unroll
      for (int n = 0; n < 4; ++n)
#pragma unroll
        for (int i = 0; i < 4; ++i) oacc[n][i] *= cb4[i];
    }

    float ts = 0.f;
    char* plbase = (char*)&Pl[w][0][0];
#pragma unroll
    for (int t4 = 0; t4 < 4; ++t4) {
      f16x4 pp;
#pragma unroll
      for (int i = 0; i < 4; ++i) {
        const float p = exp2f(sa[t4][i] - mr);
        ts += p;
        pp[i] = (_Float16)p;
      }
      // P[q=lr][kv=t4*16+lg*4+i], swizzled row (XOR bits 4-6, 8B aligned)
      *(f16x4*)(plbase + lr * 128 + ((t4 * 32 + lg * 8) ^ ((lr & 7) << 4))) = pp;
    }
    ts += __shfl_xor(ts, 16);
    ts += __shfl_xor(ts, 32);
    lsum += ts;

    // O += P V (A=P[q][kv], B=V^T[d][kv])
    const f16x8 aP0 = swzread(&Pl[w][0][0], lr, lg);
    const f16x8 aP1 = swzread(&Pl[w][0][0], lr, lg + 4);
    __builtin_amdgcn_s_setprio(1);
#pragma unroll
    for (int n = 0; n < 4; ++n) {
      const int d = n * 16 + lr;
      const f16x8 bv0 = swzread(&Vt[cur][0][0], d, lg);
      const f16x8 bv1 = swzread(&Vt[cur][0][0], d, lg + 4);
      oacc[n] = mfma16(aP0, bv0, oacc[n]);
      oacc[n] = mfma16(aP1, bv1, oacc[n]);
    }
    __builtin_amdgcn_s_setprio(0);
  }

  // epilogue: fetch lsum for q=4*lg+i, normalize, store f16
  float ls4[4];
#pragma unroll
  for (int i = 0; i < 4; ++i)
    ls4[i] = __shfl(lsum, (l & 48) + ((l >> 4) << 2) + i);
  const int b = bh >> 4, h = bh & 15;
#pragma unroll
  for (int n = 0; n < 4; ++n)
#pragma unroll
    for (int i = 0; i < 4; ++i) {
      const int row = qb + ((l >> 4) << 2) + i;
      ao[((size_t)b * SEQ + row) * EMB + h * HD_ + n * 16 + lr] =
          (_Float16)(oacc[n][i] / ls4[i]);
    }
}

extern "C" void kernel_launch(void* const* d_in, const int* in_sizes, int n_in,
                              void* d_out, int out_size, void* d_ws, size_t ws_size,
                              hipStream_t stream) {
  const float* query = (const float*)d_in[0];
  const float* Wqkv = (const float*)d_in[3];
  const float* bqkv = (const float*)d_in[4];
  const float* Wproj = (const float*)d_in[5];
  const float* bproj = (const float*)d_in[6];
  float* out = (float*)d_out;

  char* ws = (char*)d_ws;
  const size_t MB = 1024 * 1024;
  __hip_bfloat16* q_hi    = (__hip_bfloat16*)(ws + 0);        // 8MB; dead after QKV GEMMs
  __hip_bfloat16* q_lo    = (__hip_bfloat16*)(ws + 8 * MB);   // 8MB; dead after QK GEMM
  __hip_bfloat16* Wqkv_th = (__hip_bfloat16*)(ws + 16 * MB);  // 6MB (rows: q|k|v)
  __hip_bfloat16* Wqkv_tl = (__hip_bfloat16*)(ws + 22 * MB);  // 6MB
  _Float16* q_s           = (_Float16*)(ws + 28 * MB);        // 8MB [32][2048][64]
  _Float16* k_s           = (_Float16*)(ws + 36 * MB);        // 8MB
  _Float16* v_t           = (_Float16*)(ws + 44 * MB);        // 8MB [32][64][2048]
  _Float16* a_o           = (_Float16*)(ws + 0);              // aliases q_hi
  _Float16* Wproj_t       = (_Float16*)(ws + 8 * MB);         // aliases q_lo

  const int M = BATCH * SEQ;  // 4096
  k_convert_split<<<(M * EMB / 4 + 255) / 256, 256, 0, stream>>>(query, q_hi, q_lo,
                                                                 M * EMB / 4);
  k_transpose<0><<<dim3(3 * EMB / 32, EMB / 32), 256, 0, stream>>>(Wqkv, Wqkv_th,
                                                                   Wqkv_tl, EMB, 3 * EMB);
  // q,k columns: split-bf16 precision (3 MFMA)
  k_gemm<0, 1><<<dim3(16, M / 128), 256, 0, stream>>>(
      q_hi, q_lo, Wqkv_th, Wqkv_tl, bqkv, M, 2048, EMB, q_s, k_s, nullptr);
  // v columns: single bf16 (1 MFMA)
  k_gemm<2, 0><<<dim3(8, M / 128), 256, 0, stream>>>(
      q_hi, nullptr, Wqkv_th + (size_t)2048 * EMB, nullptr, bqkv, M, 1024, EMB, v_t,
      nullptr, nullptr);
  k_transpose<1><<<dim3(EMB / 32, EMB / 32), 256, 0, stream>>>(Wproj, Wproj_t, nullptr,
                                                               EMB, EMB);
  k_attn<<<dim3(1024), 256, 0, stream>>>(q_s, k_s, v_t, a_o);
  k_gemm<1, 0><<<dim3(EMB / 128, M / 128), 256, 0, stream>>>(
      a_o, nullptr, Wproj_t, nullptr, bproj, M, EMB, EMB, nullptr, nullptr, out);
}